// Round 6
// baseline (4528.813 us; speedup 1.0000x reference)
//
#include <hip/hip_runtime.h>
#include <hip/hip_fp16.h>

#define USER_NUM 120000
#define ITEM_NUM 80000
#define N_NODES (USER_NUM + ITEM_NUM)
#define N_EDGES 3200000
#define D 64
#define BSHIFT 8
#define BROWS 256
#define N_BUCKETS ((N_NODES + BROWS - 1) >> BSHIFT)   // 782
#define SCATTER_CHUNK 4096
#define COL_MASK 0x3FFFF                              // 18 bits, N_NODES < 2^18

// ---------------------------------------------------------------------------
// init: L0 (fp16) = concat(user, item)
// ---------------------------------------------------------------------------
__global__ void init_kernel(const float* __restrict__ user,
                            const float* __restrict__ item,
                            __half* __restrict__ L0) {
    const int total4 = N_NODES * D / 4;
    const int user4  = USER_NUM * D / 4;
    int idx = blockIdx.x * blockDim.x + threadIdx.x;
    const int stride = gridDim.x * blockDim.x;
    const float4* u4 = (const float4*)user;
    const float4* i4 = (const float4*)item;
    float2* o2 = (float2*)L0;                 // 4 halves = 8 B per slot
    for (; idx < total4; idx += stride) {
        float4 v = (idx < user4) ? u4[idx] : i4[idx - user4];
        union { __half2 h[2]; float2 f; } u;
        u.h[0] = __floats2half2_rn(v.x, v.y);
        u.h[1] = __floats2half2_rn(v.z, v.w);
        o2[idx] = u.f;
    }
}

// ---------------------------------------------------------------------------
// bucket histogram (LDS-binned; 782 global atomics per block)
// ---------------------------------------------------------------------------
__global__ void hist_kernel(const int* __restrict__ rows, int* __restrict__ bcount) {
    __shared__ int cnt[N_BUCKETS];
    for (int i = threadIdx.x; i < N_BUCKETS; i += 256) cnt[i] = 0;
    __syncthreads();
    int e = blockIdx.x * blockDim.x + threadIdx.x;
    const int stride = gridDim.x * blockDim.x;
    for (; e < N_EDGES; e += stride) atomicAdd(&cnt[rows[e] >> BSHIFT], 1);
    __syncthreads();
    for (int i = threadIdx.x; i < N_BUCKETS; i += 256)
        if (cnt[i]) atomicAdd(&bcount[i], cnt[i]);
}

// ---------------------------------------------------------------------------
// exclusive scan over 782 bucket counts (single wave); bstart[N_BUCKETS]=E
// ---------------------------------------------------------------------------
__global__ void scan_kernel(const int* __restrict__ bcount,
                            int* __restrict__ bstart,
                            int* __restrict__ bcursor) {
    const int lane = threadIdx.x;   // blockDim = 64
    int carry = 0;
    for (int base = 0; base < N_BUCKETS; base += 64) {
        const int i = base + lane;
        int x = (i < N_BUCKETS) ? bcount[i] : 0;
        int v = x;
        #pragma unroll
        for (int d = 1; d < 64; d <<= 1) {
            int y = __shfl_up(v, d);
            if (lane >= d) v += y;
        }
        if (i < N_BUCKETS) { const int ex = carry + v - x; bstart[i] = ex; bcursor[i] = ex; }
        carry += __shfl(v, 63);
    }
    if (lane == 0) bstart[N_BUCKETS] = carry;   // == N_EDGES
}

// ---------------------------------------------------------------------------
// LDS-binned bucket scatter: per 4096-edge chunk, count per bucket in LDS,
// reserve per-bucket run with ONE global atomic, then append. Packs
// (localrow<<18 | col, val) into int2.
// ---------------------------------------------------------------------------
__global__ void scatter_kernel(const int* __restrict__ rows,
                               const int* __restrict__ cols,
                               const float* __restrict__ vals,
                               int* __restrict__ bcursor,
                               int2* __restrict__ cv) {
    __shared__ int cnt[N_BUCKETS];
    __shared__ int gb[N_BUCKETS];
    const int t = threadIdx.x;
    for (int cbase = blockIdx.x * SCATTER_CHUNK; cbase < N_EDGES;
         cbase += gridDim.x * SCATTER_CHUNK) {
        const int cend = min(cbase + SCATTER_CHUNK, N_EDGES);
        for (int i = t; i < N_BUCKETS; i += 256) cnt[i] = 0;
        __syncthreads();
        for (int e = cbase + t; e < cend; e += 256)
            atomicAdd(&cnt[rows[e] >> BSHIFT], 1);
        __syncthreads();
        for (int i = t; i < N_BUCKETS; i += 256) {
            const int c = cnt[i];
            gb[i] = c ? atomicAdd(&bcursor[i], c) : 0;
            cnt[i] = 0;   // reuse as local cursor
        }
        __syncthreads();
        for (int e = cbase + t; e < cend; e += 256) {
            const int r = rows[e];
            const int b = r >> BSHIFT;
            const int off = atomicAdd(&cnt[b], 1);
            cv[gb[b] + off] =
                make_int2(((r & (BROWS - 1)) << 18) | cols[e], __float_as_int(vals[e]));
        }
        __syncthreads();
    }
}

// ---------------------------------------------------------------------------
// SpMM: one block per 256-row bucket. 64 KB LDS f32 accumulator. 8 waves;
// each wave stages 64 (packed,val) pairs with one coalesced load, broadcasts
// via __shfl (wave-uniform bounds), gathers fp16 rows (128 B/edge), and
// ds_add_f32 into the accumulator (bank-conflict-free: bank == lane%32).
// ---------------------------------------------------------------------------
__global__ __launch_bounds__(512) void spmm_kernel(const int* __restrict__ bstart,
                                                   const int2* __restrict__ cv,
                                                   const __half* __restrict__ in,
                                                   __half* __restrict__ out) {
    __shared__ float acc[BROWS * D];   // 64 KB
    const int b = blockIdx.x;
    const int t = threadIdx.x;
    float4* a4 = (float4*)acc;
    #pragma unroll
    for (int i = t; i < BROWS * D / 4; i += 512)
        a4[i] = make_float4(0.f, 0.f, 0.f, 0.f);
    __syncthreads();

    const int start = bstart[b];
    const int end   = bstart[b + 1];
    const int lane = t & 63;
    const int wid  = t >> 6;           // 0..7

    for (int base = start + (wid << 6); base < end; base += 512) {
        const int rem = end - base;    // wave-uniform
        if (rem >= 64) {
            const int2 p = cv[base + lane];
            #pragma unroll 8
            for (int k = 0; k < 64; ++k) {
                const int   pk = __shfl(p.x, k);
                const float v  = __int_as_float(__shfl(p.y, k));
                const float x  = __half2float(in[((size_t)(pk & COL_MASK) << 6) + lane]);
                atomicAdd(&acc[((pk >> 18) << 6) + lane], v * x);
            }
        } else {
            const int2 p = cv[base + min(lane, rem - 1)];
            for (int k = 0; k < rem; ++k) {     // uniform bound: no lane exits
                const int   pk = __shfl(p.x, k);
                const float v  = __int_as_float(__shfl(p.y, k));
                const float x  = __half2float(in[((size_t)(pk & COL_MASK) << 6) + lane]);
                atomicAdd(&acc[((pk >> 18) << 6) + lane], v * x);
            }
        }
    }
    __syncthreads();

    // write bucket rows as fp16
    const int nrows = min(BROWS, N_NODES - (b << BSHIFT));
    const int n4 = (nrows * D) / 4;
    float2* o2 = (float2*)out;                        // 4 halves per slot
    const int gb4 = (b << BSHIFT) * (D / 4);
    for (int i = t; i < n4; i += 512) {
        const float4 a = a4[i];
        union { __half2 h[2]; float2 f; } u;
        u.h[0] = __floats2half2_rn(a.x, a.y);
        u.h[1] = __floats2half2_rn(a.z, a.w);
        o2[gb4 + i] = u.f;
    }
}

// ---------------------------------------------------------------------------
// pooled = L0 + L1 + L2 + L3 (fp16 reads, f32 write)
// ---------------------------------------------------------------------------
__global__ void pool_kernel(const __half* __restrict__ L0,
                            const __half* __restrict__ L1,
                            const __half* __restrict__ L2,
                            const __half* __restrict__ L3,
                            float* __restrict__ pooled) {
    const int total4 = N_NODES * D / 4;
    int idx = blockIdx.x * blockDim.x + threadIdx.x;
    const int stride = gridDim.x * blockDim.x;
    const float2* p0 = (const float2*)L0;
    const float2* p1 = (const float2*)L1;
    const float2* p2 = (const float2*)L2;
    const float2* p3 = (const float2*)L3;
    float4* o4 = (float4*)pooled;
    for (; idx < total4; idx += stride) {
        union { float2 f; __half2 h[2]; } a0, a1, a2, a3;
        a0.f = p0[idx]; a1.f = p1[idx]; a2.f = p2[idx]; a3.f = p3[idx];
        const float2 l0 = __half22float2(a0.h[0]), h0 = __half22float2(a0.h[1]);
        const float2 l1 = __half22float2(a1.h[0]), h1 = __half22float2(a1.h[1]);
        const float2 l2 = __half22float2(a2.h[0]), h2 = __half22float2(a2.h[1]);
        const float2 l3 = __half22float2(a3.h[0]), h3 = __half22float2(a3.h[1]);
        o4[idx] = make_float4(l0.x + l1.x + l2.x + l3.x,
                              l0.y + l1.y + l2.y + l3.y,
                              h0.x + h1.x + h2.x + h3.x,
                              h0.y + h1.y + h2.y + h3.y);
    }
}

extern "C" void kernel_launch(void* const* d_in, const int* in_sizes, int n_in,
                              void* d_out, int out_size, void* d_ws, size_t ws_size,
                              hipStream_t stream) {
    const float* user = (const float*)d_in[0];
    const float* item = (const float*)d_in[1];
    const int*   rows = (const int*)d_in[2];
    const int*   cols = (const int*)d_in[3];
    const float* vals = (const float*)d_in[4];

    float* pooled = (float*)d_out;

    // workspace layout
    char* p = (char*)d_ws;
    const size_t embN = (size_t)N_NODES * D;
    __half* L0 = (__half*)p;  p += embN * 2;     // 25.6 MB
    __half* L1 = (__half*)p;  p += embN * 2;
    __half* L2 = (__half*)p;  p += embN * 2;
    __half* L3 = (__half*)p;  p += embN * 2;
    int2*  cv      = (int2*)p;  p += (size_t)N_EDGES * 8;   // 25.6 MB
    int*   bcount  = (int*)p;   p += (size_t)(N_BUCKETS + 1) * 4;
    int*   bstart  = (int*)p;   p += (size_t)(N_BUCKETS + 1) * 4;
    int*   bcursor = (int*)p;   p += (size_t)N_BUCKETS * 4;

    const dim3 blk256(256);
    hipMemsetAsync(bcount, 0, (size_t)(N_BUCKETS + 1) * 4, stream);

    init_kernel<<<2048, blk256, 0, stream>>>(user, item, L0);
    hist_kernel<<<2048, blk256, 0, stream>>>(rows, bcount);
    scan_kernel<<<1, 64, 0, stream>>>(bcount, bstart, bcursor);
    scatter_kernel<<<(N_EDGES + SCATTER_CHUNK - 1) / SCATTER_CHUNK, blk256, 0, stream>>>(
        rows, cols, vals, bcursor, cv);

    spmm_kernel<<<N_BUCKETS, 512, 0, stream>>>(bstart, cv, L0, L1);
    spmm_kernel<<<N_BUCKETS, 512, 0, stream>>>(bstart, cv, L1, L2);
    spmm_kernel<<<N_BUCKETS, 512, 0, stream>>>(bstart, cv, L2, L3);

    pool_kernel<<<2048, blk256, 0, stream>>>(L0, L1, L2, L3, pooled);
}

// Round 7
// 674.283 us; speedup vs baseline: 6.7165x; 6.7165x over previous
//
#include <hip/hip_runtime.h>
#include <hip/hip_fp16.h>

#define USER_NUM 120000
#define ITEM_NUM 80000
#define N_NODES (USER_NUM + ITEM_NUM)
#define N_EDGES 3200000
#define D 64
#define BSHIFT 8
#define BROWS 256
#define N_BUCKETS ((N_NODES + BROWS - 1) >> BSHIFT)   // 782
#define SCATTER_CHUNK 4096
#define COL_MASK 0x3FFFF                              // 18 bits, N_NODES < 2^18

// ---------------------------------------------------------------------------
// init: L0 (fp16) = concat(user, item)
// ---------------------------------------------------------------------------
__global__ void init_kernel(const float* __restrict__ user,
                            const float* __restrict__ item,
                            __half* __restrict__ L0) {
    const int total4 = N_NODES * D / 4;
    const int user4  = USER_NUM * D / 4;
    int idx = blockIdx.x * blockDim.x + threadIdx.x;
    const int stride = gridDim.x * blockDim.x;
    const float4* u4 = (const float4*)user;
    const float4* i4 = (const float4*)item;
    float2* o2 = (float2*)L0;                 // 4 halves = 8 B per slot
    for (; idx < total4; idx += stride) {
        float4 v = (idx < user4) ? u4[idx] : i4[idx - user4];
        union { __half2 h[2]; float2 f; } u;
        u.h[0] = __floats2half2_rn(v.x, v.y);
        u.h[1] = __floats2half2_rn(v.z, v.w);
        o2[idx] = u.f;
    }
}

// ---------------------------------------------------------------------------
// bucket histogram (LDS-binned; <=782 global atomics per block)
// ---------------------------------------------------------------------------
__global__ void hist_kernel(const int* __restrict__ rows, int* __restrict__ bcount) {
    __shared__ int cnt[N_BUCKETS];
    for (int i = threadIdx.x; i < N_BUCKETS; i += 256) cnt[i] = 0;
    __syncthreads();
    int e = blockIdx.x * blockDim.x + threadIdx.x;
    const int stride = gridDim.x * blockDim.x;
    for (; e < N_EDGES; e += stride) atomicAdd(&cnt[rows[e] >> BSHIFT], 1);
    __syncthreads();
    for (int i = threadIdx.x; i < N_BUCKETS; i += 256)
        if (cnt[i]) atomicAdd(&bcount[i], cnt[i]);
}

// ---------------------------------------------------------------------------
// exclusive scan over 782 bucket counts (single wave); bstart[N_BUCKETS]=E;
// also writes the row_start sentinel.
// ---------------------------------------------------------------------------
__global__ void scan_kernel(const int* __restrict__ bcount,
                            int* __restrict__ bstart,
                            int* __restrict__ bcursor,
                            int* __restrict__ row_start) {
    const int lane = threadIdx.x;   // blockDim = 64
    int carry = 0;
    for (int base = 0; base < N_BUCKETS; base += 64) {
        const int i = base + lane;
        int x = (i < N_BUCKETS) ? bcount[i] : 0;
        int v = x;
        #pragma unroll
        for (int d = 1; d < 64; d <<= 1) {
            int y = __shfl_up(v, d);
            if (lane >= d) v += y;
        }
        if (i < N_BUCKETS) { const int ex = carry + v - x; bstart[i] = ex; bcursor[i] = ex; }
        carry += __shfl(v, 63);
    }
    if (lane == 0) { bstart[N_BUCKETS] = carry; row_start[N_NODES] = carry; }
}

// ---------------------------------------------------------------------------
// LDS-binned bucket scatter: per 4096-edge chunk, count per bucket in LDS,
// reserve per-bucket run with ONE global atomic, then append. Packs
// (localrow<<18 | col, val) into int2.
// ---------------------------------------------------------------------------
__global__ void scatter_kernel(const int* __restrict__ rows,
                               const int* __restrict__ cols,
                               const float* __restrict__ vals,
                               int* __restrict__ bcursor,
                               int2* __restrict__ cv_tmp) {
    __shared__ int cnt[N_BUCKETS];
    __shared__ int gb[N_BUCKETS];
    const int t = threadIdx.x;
    for (int cbase = blockIdx.x * SCATTER_CHUNK; cbase < N_EDGES;
         cbase += gridDim.x * SCATTER_CHUNK) {
        const int cend = min(cbase + SCATTER_CHUNK, N_EDGES);
        for (int i = t; i < N_BUCKETS; i += 256) cnt[i] = 0;
        __syncthreads();
        for (int e = cbase + t; e < cend; e += 256)
            atomicAdd(&cnt[rows[e] >> BSHIFT], 1);
        __syncthreads();
        for (int i = t; i < N_BUCKETS; i += 256) {
            const int c = cnt[i];
            gb[i] = c ? atomicAdd(&bcursor[i], c) : 0;
            cnt[i] = 0;   // reuse as local cursor
        }
        __syncthreads();
        for (int e = cbase + t; e < cend; e += 256) {
            const int r = rows[e];
            const int b = r >> BSHIFT;
            const int off = atomicAdd(&cnt[b], 1);
            cv_tmp[gb[b] + off] =
                make_int2(((r & (BROWS - 1)) << 18) | cols[e], __float_as_int(vals[e]));
        }
        __syncthreads();
    }
}

// ---------------------------------------------------------------------------
// per-bucket row sort: block b sorts its bucket's edges by local row via an
// LDS 256-bin counting sort. Writes row-sorted (col,val) into cv and the
// global row_start. All scatter writes land in the bucket's own contiguous
// ~32KB range (L2-resident).
// ---------------------------------------------------------------------------
__global__ void rowsort_kernel(const int* __restrict__ bstart,
                               const int2* __restrict__ cv_tmp,
                               int2* __restrict__ cv,
                               int* __restrict__ row_start) {
    __shared__ int hist[BROWS];
    __shared__ int sstart[BROWS];
    __shared__ int cursor[BROWS];
    const int b = blockIdx.x;
    const int t = threadIdx.x;            // blockDim = 256
    const int start = bstart[b];
    const int end   = bstart[b + 1];
    hist[t] = 0;
    __syncthreads();
    for (int e = start + t; e < end; e += 256)
        atomicAdd(&hist[(cv_tmp[e].x >> 18) & (BROWS - 1)], 1);
    __syncthreads();
    if (t < 64) {                         // wave 0 scans the 256 bins
        int carry = 0;
        for (int base = 0; base < BROWS; base += 64) {
            const int x = hist[base + t];
            int v = x;
            #pragma unroll
            for (int d = 1; d < 64; d <<= 1) {
                int y = __shfl_up(v, d);
                if (t >= d) v += y;
            }
            sstart[base + t] = carry + v - x;
            carry += __shfl(v, 63);
        }
    }
    __syncthreads();
    cursor[t] = sstart[t];
    const int grow = (b << BSHIFT) + t;
    if (grow < N_NODES) row_start[grow] = start + sstart[t];
    __syncthreads();
    for (int e = start + t; e < end; e += 256) {
        const int2 p = cv_tmp[e];
        const int lr = (p.x >> 18) & (BROWS - 1);
        const int pos = start + atomicAdd(&cursor[lr], 1);
        cv[pos] = make_int2(p.x & COL_MASK, p.y);
    }
}

// ---------------------------------------------------------------------------
// CSR SpMM, fp16 in/out, f32 accumulate. One wave per row; 8 groups x 8
// lanes; group g handles edge k8+g; lane-in-group gl holds dims
// [8*gl, 8*gl+8) loaded as one dwordx4 (8 halves = 128B/edge total).
// (col,val) staged with one coalesced 64-lane load, broadcast via __shfl
// with WAVE-UNIFORM loop bounds (no lane ever exits early). Cross-group
// reduce via shfl_xor(8/16/32); lanes 0..7 write the fp16 row.
// ---------------------------------------------------------------------------
#define EDGE_BODY(c, v) do {                                                   \
    const float4 raw = *(const float4*)&in[((size_t)(c) << 6) + (gl << 3)];    \
    union { float4 f; __half2 h[4]; } u_; u_.f = raw;                          \
    const float2 x0 = __half22float2(u_.h[0]);                                 \
    const float2 x1 = __half22float2(u_.h[1]);                                 \
    const float2 x2 = __half22float2(u_.h[2]);                                 \
    const float2 x3 = __half22float2(u_.h[3]);                                 \
    a[0] = fmaf((v), x0.x, a[0]); a[1] = fmaf((v), x0.y, a[1]);                \
    a[2] = fmaf((v), x1.x, a[2]); a[3] = fmaf((v), x1.y, a[3]);                \
    a[4] = fmaf((v), x2.x, a[4]); a[5] = fmaf((v), x2.y, a[5]);                \
    a[6] = fmaf((v), x3.x, a[6]); a[7] = fmaf((v), x3.y, a[7]);                \
} while (0)

__global__ __launch_bounds__(256) void spmm_kernel(const int* __restrict__ row_start,
                                                   const int2* __restrict__ cv,
                                                   const __half* __restrict__ in,
                                                   __half* __restrict__ out) {
    const int lane = threadIdx.x & 63;
    const int row = (blockIdx.x * blockDim.x + threadIdx.x) >> 6;
    if (row >= N_NODES) return;
    const int g  = lane >> 3;    // edge group 0..7
    const int gl = lane & 7;     // dim-slice lane
    const int start = row_start[row];
    const int end   = row_start[row + 1];
    float a[8] = {0.f, 0.f, 0.f, 0.f, 0.f, 0.f, 0.f, 0.f};
    for (int chunk = start; chunk < end; chunk += 64) {
        const int rem = min(64, end - chunk);        // wave-uniform
        const int2 p = cv[chunk + min(lane, rem - 1)];
        if (rem == 64) {
            #pragma unroll
            for (int k8 = 0; k8 < 64; k8 += 8) {
                const int k = k8 + g;
                const int   c = __shfl(p.x, k);
                const float v = __int_as_float(__shfl(p.y, k));
                EDGE_BODY(c, v);
            }
        } else {
            for (int k8 = 0; k8 < rem; k8 += 8) {    // uniform bounds
                const int k = k8 + g;
                const bool valid = k < rem;
                const int kc = valid ? k : rem - 1;
                const int   c = __shfl(p.x, kc);
                float v = __int_as_float(__shfl(p.y, kc));
                if (!valid) v = 0.f;
                EDGE_BODY(c, v);
            }
        }
    }
    #pragma unroll
    for (int i = 0; i < 8; ++i) {
        a[i] += __shfl_xor(a[i], 8);
        a[i] += __shfl_xor(a[i], 16);
        a[i] += __shfl_xor(a[i], 32);
    }
    if (lane < 8) {
        union { float4 f4; __half2 h[4]; } o;
        o.h[0] = __floats2half2_rn(a[0], a[1]);
        o.h[1] = __floats2half2_rn(a[2], a[3]);
        o.h[2] = __floats2half2_rn(a[4], a[5]);
        o.h[3] = __floats2half2_rn(a[6], a[7]);
        *(float4*)&out[((size_t)row << 6) + (lane << 3)] = o.f4;
    }
}

// ---------------------------------------------------------------------------
// pooled = L0 + L1 + L2 + L3 (fp16 reads, f32 write)
// ---------------------------------------------------------------------------
__global__ void pool_kernel(const __half* __restrict__ L0,
                            const __half* __restrict__ L1,
                            const __half* __restrict__ L2,
                            const __half* __restrict__ L3,
                            float* __restrict__ pooled) {
    const int total4 = N_NODES * D / 4;
    int idx = blockIdx.x * blockDim.x + threadIdx.x;
    const int stride = gridDim.x * blockDim.x;
    const float2* p0 = (const float2*)L0;
    const float2* p1 = (const float2*)L1;
    const float2* p2 = (const float2*)L2;
    const float2* p3 = (const float2*)L3;
    float4* o4 = (float4*)pooled;
    for (; idx < total4; idx += stride) {
        union { float2 f; __half2 h[2]; } a0, a1, a2, a3;
        a0.f = p0[idx]; a1.f = p1[idx]; a2.f = p2[idx]; a3.f = p3[idx];
        const float2 l0 = __half22float2(a0.h[0]), h0 = __half22float2(a0.h[1]);
        const float2 l1 = __half22float2(a1.h[0]), h1 = __half22float2(a1.h[1]);
        const float2 l2 = __half22float2(a2.h[0]), h2 = __half22float2(a2.h[1]);
        const float2 l3 = __half22float2(a3.h[0]), h3 = __half22float2(a3.h[1]);
        o4[idx] = make_float4(l0.x + l1.x + l2.x + l3.x,
                              l0.y + l1.y + l2.y + l3.y,
                              h0.x + h1.x + h2.x + h3.x,
                              h0.y + h1.y + h2.y + h3.y);
    }
}

extern "C" void kernel_launch(void* const* d_in, const int* in_sizes, int n_in,
                              void* d_out, int out_size, void* d_ws, size_t ws_size,
                              hipStream_t stream) {
    const float* user = (const float*)d_in[0];
    const float* item = (const float*)d_in[1];
    const int*   rows = (const int*)d_in[2];
    const int*   cols = (const int*)d_in[3];
    const float* vals = (const float*)d_in[4];

    float* pooled = (float*)d_out;

    // workspace layout (cv_tmp overlays L2: L2 is only written by spmm #2,
    // after cv_tmp has been fully consumed by rowsort)
    char* p = (char*)d_ws;
    const size_t embB = (size_t)N_NODES * D * 2;    // 25.6 MB per fp16 layer
    __half* L0 = (__half*)p;  p += embB;
    __half* L1 = (__half*)p;  p += embB;
    __half* L2 = (__half*)p;  p += embB;
    __half* L3 = (__half*)p;  p += embB;
    int2* cv_tmp = (int2*)L2;                       // overlay, 25.6 MB
    int2* cv      = (int2*)p;  p += (size_t)N_EDGES * 8;            // 25.6 MB
    int*  row_start = (int*)p; p += (size_t)(N_NODES + 1) * 4;      // 0.8 MB
    int*  bcount  = (int*)p;   p += (size_t)(N_BUCKETS + 1) * 4;
    int*  bstart  = (int*)p;   p += (size_t)(N_BUCKETS + 1) * 4;
    int*  bcursor = (int*)p;   p += (size_t)N_BUCKETS * 4;

    const dim3 blk256(256);
    hipMemsetAsync(bcount, 0, (size_t)(N_BUCKETS + 1) * 4, stream);

    init_kernel<<<2048, blk256, 0, stream>>>(user, item, L0);
    hist_kernel<<<2048, blk256, 0, stream>>>(rows, bcount);
    scan_kernel<<<1, 64, 0, stream>>>(bcount, bstart, bcursor, row_start);
    scatter_kernel<<<(N_EDGES + SCATTER_CHUNK - 1) / SCATTER_CHUNK, blk256, 0, stream>>>(
        rows, cols, vals, bcursor, cv_tmp);
    rowsort_kernel<<<N_BUCKETS, blk256, 0, stream>>>(bstart, cv_tmp, cv, row_start);

    const dim3 grid_spmm((N_NODES + 3) / 4);        // 4 rows (waves) per block
    spmm_kernel<<<grid_spmm, blk256, 0, stream>>>(row_start, cv, L0, L1);
    spmm_kernel<<<grid_spmm, blk256, 0, stream>>>(row_start, cv, L1, L2);
    spmm_kernel<<<grid_spmm, blk256, 0, stream>>>(row_start, cv, L2, L3);

    pool_kernel<<<2048, blk256, 0, stream>>>(L0, L1, L2, L3, pooled);
}

// Round 8
// 515.082 us; speedup vs baseline: 8.7924x; 1.3091x over previous
//
#include <hip/hip_runtime.h>
#include <hip/hip_fp16.h>

#define USER_NUM 120000
#define ITEM_NUM 80000
#define N_NODES (USER_NUM + ITEM_NUM)
#define N_EDGES 3200000
#define D 64
#define BSHIFT 8
#define BROWS 256
#define N_BUCKETS ((N_NODES + BROWS - 1) >> BSHIFT)   // 782
#define BPAD 5120                                     // slots per bucket (mean 4092, max~4310)
#define SCATTER_CHUNK 4096
#define COL_MASK 0x3FFFF                              // 18 bits, N_NODES < 2^18

// ---------------------------------------------------------------------------
// init: L0 (fp16) = concat(user, item)
// ---------------------------------------------------------------------------
__global__ void init_kernel(const float* __restrict__ user,
                            const float* __restrict__ item,
                            __half* __restrict__ L0) {
    const int total4 = N_NODES * D / 4;
    const int user4  = USER_NUM * D / 4;
    int idx = blockIdx.x * blockDim.x + threadIdx.x;
    const int stride = gridDim.x * blockDim.x;
    const float4* u4 = (const float4*)user;
    const float4* i4 = (const float4*)item;
    float2* o2 = (float2*)L0;                 // 4 halves = 8 B per slot
    for (; idx < total4; idx += stride) {
        float4 v = (idx < user4) ? u4[idx] : i4[idx - user4];
        union { __half2 h[2]; float2 f; } u;
        u.h[0] = __floats2half2_rn(v.x, v.y);
        u.h[1] = __floats2half2_rn(v.z, v.w);
        o2[idx] = u.f;
    }
}

// ---------------------------------------------------------------------------
// LDS-binned bucket scatter into PADDED per-bucket regions (no global scan
// needed). Per 4096-edge chunk: LDS count per bucket, reserve a run with one
// global atomic on bcursor (zero-initialized), append. Packs
// (localrow<<18 | col, val) into int2.
// ---------------------------------------------------------------------------
__global__ void scatter_kernel(const int* __restrict__ rows,
                               const int* __restrict__ cols,
                               const float* __restrict__ vals,
                               int* __restrict__ bcursor,
                               int2* __restrict__ cv_tmp) {
    __shared__ int cnt[N_BUCKETS];
    __shared__ int gb[N_BUCKETS];
    const int t = threadIdx.x;
    for (int cbase = blockIdx.x * SCATTER_CHUNK; cbase < N_EDGES;
         cbase += gridDim.x * SCATTER_CHUNK) {
        const int cend = min(cbase + SCATTER_CHUNK, N_EDGES);
        for (int i = t; i < N_BUCKETS; i += 256) cnt[i] = 0;
        __syncthreads();
        for (int e = cbase + t; e < cend; e += 256)
            atomicAdd(&cnt[rows[e] >> BSHIFT], 1);
        __syncthreads();
        for (int i = t; i < N_BUCKETS; i += 256) {
            const int c = cnt[i];
            gb[i] = c ? atomicAdd(&bcursor[i], c) : 0;
            cnt[i] = 0;   // reuse as local cursor
        }
        __syncthreads();
        for (int e = cbase + t; e < cend; e += 256) {
            const int r = rows[e];
            const int b = r >> BSHIFT;
            const int off = atomicAdd(&cnt[b], 1);
            cv_tmp[(size_t)b * BPAD + gb[b] + off] =
                make_int2(((r & (BROWS - 1)) << 18) | cols[e], __float_as_int(vals[e]));
        }
        __syncthreads();
    }
}

// ---------------------------------------------------------------------------
// per-bucket row sort (LDS 256-bin counting sort). Block b reads its bucket's
// padded run (count = bcursor[b]), writes row-sorted (col,val) into cv's
// padded bucket region, and row_se[row] = (abs start, abs end).
// ---------------------------------------------------------------------------
__global__ void rowsort_kernel(const int* __restrict__ bcursor,
                               const int2* __restrict__ cv_tmp,
                               int2* __restrict__ cv,
                               int2* __restrict__ row_se) {
    __shared__ int hist[BROWS];
    __shared__ int sstart[BROWS];
    __shared__ int cursor[BROWS];
    const int b = blockIdx.x;
    const int t = threadIdx.x;            // blockDim = 256
    const int base = b * BPAD;
    const int count = bcursor[b];
    hist[t] = 0;
    __syncthreads();
    for (int e = t; e < count; e += 256)
        atomicAdd(&hist[(cv_tmp[base + e].x >> 18) & (BROWS - 1)], 1);
    __syncthreads();
    if (t < 64) {                         // wave 0 scans the 256 bins
        int carry = 0;
        for (int bb = 0; bb < BROWS; bb += 64) {
            const int x = hist[bb + t];
            int v = x;
            #pragma unroll
            for (int d = 1; d < 64; d <<= 1) {
                int y = __shfl_up(v, d);
                if (t >= d) v += y;
            }
            sstart[bb + t] = carry + v - x;
            carry += __shfl(v, 63);
        }
    }
    __syncthreads();
    cursor[t] = sstart[t];
    const int grow = (b << BSHIFT) + t;
    if (grow < N_NODES)
        row_se[grow] = make_int2(base + sstart[t], base + sstart[t] + hist[t]);
    __syncthreads();
    for (int e = t; e < count; e += 256) {
        const int2 p = cv_tmp[base + e];
        const int lr = (p.x >> 18) & (BROWS - 1);
        const int pos = base + atomicAdd(&cursor[lr], 1);
        cv[pos] = make_int2(p.x & COL_MASK, p.y);
    }
}

// ---------------------------------------------------------------------------
// CSR SpMM, fp16 in, f32 accumulate. 16 lanes per row, 4 rows per wave:
// no cross-lane ops at all. (col,val) is a 16-lane broadcast load (one
// transaction), 4-deep unrolled -> 4 cv + 4 gather loads in flight per
// group. Lane l holds dims [4l, 4l+4). Group-level loop divergence is
// masked-lane waste only (no extra fetches). last=1: fuse the pooling --
// pooled = L0+L1+L2+acc (f32), L3 never materialized.
// ---------------------------------------------------------------------------
__global__ __launch_bounds__(256) void spmm_kernel(const int2* __restrict__ row_se,
                                                   const int2* __restrict__ cv,
                                                   const __half* __restrict__ in,
                                                   __half* __restrict__ out,
                                                   const __half* __restrict__ P0,
                                                   const __half* __restrict__ P1,
                                                   float* __restrict__ pooled,
                                                   int last) {
    const int row = (blockIdx.x * blockDim.x + threadIdx.x) >> 4;
    const int l   = threadIdx.x & 15;
    if (row >= N_NODES) return;
    const int2 se = row_se[row];
    float a0 = 0.f, a1 = 0.f, a2 = 0.f, a3 = 0.f;
    for (int e = se.x; e < se.y; e += 4) {
        #pragma unroll
        for (int u = 0; u < 4; ++u) {
            const int ee = e + u;
            const bool valid = ee < se.y;
            const int2 p = cv[valid ? ee : se.x];          // clamped: always in-bounds
            const float v = valid ? __int_as_float(p.y) : 0.f;
            const float2 raw = *(const float2*)&in[((size_t)p.x << 6) + (l << 2)];
            union { float2 f; __half2 h[2]; } q; q.f = raw;
            const float2 x0 = __half22float2(q.h[0]);
            const float2 x1 = __half22float2(q.h[1]);
            a0 = fmaf(v, x0.x, a0); a1 = fmaf(v, x0.y, a1);
            a2 = fmaf(v, x1.x, a2); a3 = fmaf(v, x1.y, a3);
        }
    }
    const size_t off = ((size_t)row << 6) + (l << 2);
    if (!last) {
        union { float2 f; __half2 h[2]; } o;
        o.h[0] = __floats2half2_rn(a0, a1);
        o.h[1] = __floats2half2_rn(a2, a3);
        *(float2*)&out[off] = o.f;
    } else {
        union { float2 f; __half2 h[2]; } q0, q1, q2;
        q0.f = *(const float2*)&P0[off];       // L0 row slice
        q1.f = *(const float2*)&P1[off];       // L1 row slice
        q2.f = *(const float2*)&in[off];       // L2 row slice (== gather source)
        const float2 s00 = __half22float2(q0.h[0]), s01 = __half22float2(q0.h[1]);
        const float2 s10 = __half22float2(q1.h[0]), s11 = __half22float2(q1.h[1]);
        const float2 s20 = __half22float2(q2.h[0]), s21 = __half22float2(q2.h[1]);
        *(float4*)&pooled[off] = make_float4(a0 + s00.x + s10.x + s20.x,
                                             a1 + s00.y + s10.y + s20.y,
                                             a2 + s01.x + s11.x + s21.x,
                                             a3 + s01.y + s11.y + s21.y);
    }
}

extern "C" void kernel_launch(void* const* d_in, const int* in_sizes, int n_in,
                              void* d_out, int out_size, void* d_ws, size_t ws_size,
                              hipStream_t stream) {
    const float* user = (const float*)d_in[0];
    const float* item = (const float*)d_in[1];
    const int*   rows = (const int*)d_in[2];
    const int*   cols = (const int*)d_in[3];
    const float* vals = (const float*)d_in[4];

    float* pooled = (float*)d_out;

    // workspace layout. cv_tmp overlays L1+L2 (51.2 MB >= 32 MB): it is dead
    // after rowsort, before spmm1 first writes L1.
    char* p = (char*)d_ws;
    const size_t embB = (size_t)N_NODES * D * 2;    // 25.6 MB per fp16 layer
    __half* L0 = (__half*)p;  p += embB;
    __half* L1 = (__half*)p;  p += embB;
    __half* L2 = (__half*)p;  p += embB;
    int2* cv_tmp = (int2*)L1;                       // overlay, 32 MB
    int2* cv     = (int2*)p;   p += (size_t)N_BUCKETS * BPAD * 8;   // 32 MB
    int2* row_se = (int2*)p;   p += (size_t)N_NODES * 8;            // 1.6 MB
    int*  bcursor = (int*)p;   p += (size_t)N_BUCKETS * 4;

    const dim3 blk256(256);
    hipMemsetAsync(bcursor, 0, (size_t)N_BUCKETS * 4, stream);

    init_kernel<<<2048, blk256, 0, stream>>>(user, item, L0);
    scatter_kernel<<<(N_EDGES + SCATTER_CHUNK - 1) / SCATTER_CHUNK, blk256, 0, stream>>>(
        rows, cols, vals, bcursor, cv_tmp);
    rowsort_kernel<<<N_BUCKETS, blk256, 0, stream>>>(bcursor, cv_tmp, cv, row_se);

    const dim3 grid_spmm((N_NODES * 16 + 255) / 256);   // 16 rows per block
    spmm_kernel<<<grid_spmm, blk256, 0, stream>>>(row_se, cv, L0, L1, nullptr, nullptr, nullptr, 0);
    spmm_kernel<<<grid_spmm, blk256, 0, stream>>>(row_se, cv, L1, L2, nullptr, nullptr, nullptr, 0);
    spmm_kernel<<<grid_spmm, blk256, 0, stream>>>(row_se, cv, L2, nullptr, L0, L1, pooled, 1);
}

// Round 9
// 503.799 us; speedup vs baseline: 8.9893x; 1.0224x over previous
//
#include <hip/hip_runtime.h>
#include <hip/hip_fp16.h>

#define USER_NUM 120000
#define ITEM_NUM 80000
#define N_NODES (USER_NUM + ITEM_NUM)
#define N_EDGES 3200000
#define D 64
#define BSHIFT 8
#define BROWS 256
#define N_BUCKETS ((N_NODES + BROWS - 1) >> BSHIFT)   // 782
#define BPAD 5120                                     // slots per bucket (mean 4092, max~4310)
#define SCATTER_CHUNK 4096
#define COL_MASK 0x3FFFF                              // 18 bits, N_NODES < 2^18

// ---------------------------------------------------------------------------
// init: L0 (fp16) = concat(user, item)
// ---------------------------------------------------------------------------
__global__ void init_kernel(const float* __restrict__ user,
                            const float* __restrict__ item,
                            __half* __restrict__ L0) {
    const int total4 = N_NODES * D / 4;
    const int user4  = USER_NUM * D / 4;
    int idx = blockIdx.x * blockDim.x + threadIdx.x;
    const int stride = gridDim.x * blockDim.x;
    const float4* u4 = (const float4*)user;
    const float4* i4 = (const float4*)item;
    float2* o2 = (float2*)L0;                 // 4 halves = 8 B per slot
    for (; idx < total4; idx += stride) {
        float4 v = (idx < user4) ? u4[idx] : i4[idx - user4];
        union { __half2 h[2]; float2 f; } u;
        u.h[0] = __floats2half2_rn(v.x, v.y);
        u.h[1] = __floats2half2_rn(v.z, v.w);
        o2[idx] = u.f;
    }
}

// ---------------------------------------------------------------------------
// LDS-staged bucket scatter: per 4096-edge chunk, bin edges into a 32 KB LDS
// staging buffer in bucket-sorted order (hist -> local scan -> place), then
// copy out LINEARLY so consecutive threads write consecutive slots of each
// bucket run (coalesced, whole-line writes). One global atomic per
// (bucket,chunk) reserves the run. Packs (localrow<<18 | col, val).
// ---------------------------------------------------------------------------
__global__ __launch_bounds__(256) void scatter_kernel(const int* __restrict__ rows,
                                                      const int* __restrict__ cols,
                                                      const float* __restrict__ vals,
                                                      int* __restrict__ bcursor,
                                                      int2* __restrict__ cv_tmp) {
    __shared__ int cnt[N_BUCKETS];               // hist, then local cursor
    __shared__ int lstart[N_BUCKETS];            // local exclusive scan
    __shared__ int gbase[N_BUCKETS];             // reserved global run start
    __shared__ int2 stage[SCATTER_CHUNK];        // 32 KB bucket-sorted chunk
    __shared__ unsigned short sbucket[SCATTER_CHUNK];
    const int t = threadIdx.x;
    for (int cbase = blockIdx.x * SCATTER_CHUNK; cbase < N_EDGES;
         cbase += gridDim.x * SCATTER_CHUNK) {
        const int csize = min(SCATTER_CHUNK, N_EDGES - cbase);
        for (int i = t; i < N_BUCKETS; i += 256) cnt[i] = 0;
        __syncthreads();
        // 1) local histogram
        for (int e = t; e < csize; e += 256)
            atomicAdd(&cnt[rows[cbase + e] >> BSHIFT], 1);
        __syncthreads();
        // 2a) reserve global runs (one atomic per non-empty bucket)
        for (int i = t; i < N_BUCKETS; i += 256) {
            const int c = cnt[i];
            gbase[i] = c ? atomicAdd(&bcursor[i], c) : 0;
        }
        // 2b) wave 0: local exclusive scan of cnt -> lstart
        if (t < 64) {
            int carry = 0;
            for (int base = 0; base < N_BUCKETS; base += 64) {
                const int i = base + t;
                const int x = (i < N_BUCKETS) ? cnt[i] : 0;
                int v = x;
                #pragma unroll
                for (int d = 1; d < 64; d <<= 1) {
                    int y = __shfl_up(v, d);
                    if (t >= d) v += y;
                }
                if (i < N_BUCKETS) lstart[i] = carry + v - x;
                carry += __shfl(v, 63);
            }
        }
        __syncthreads();
        // 2c) cnt becomes the local cursor
        for (int i = t; i < N_BUCKETS; i += 256) cnt[i] = lstart[i];
        __syncthreads();
        // 3) place edges into LDS in bucket-sorted order
        for (int e = t; e < csize; e += 256) {
            const int r = rows[cbase + e];
            const int b = r >> BSHIFT;
            const int off = atomicAdd(&cnt[b], 1);
            stage[off] = make_int2(((r & (BROWS - 1)) << 18) | cols[cbase + e],
                                   __float_as_int(vals[cbase + e]));
            sbucket[off] = (unsigned short)b;
        }
        __syncthreads();
        // 4) linear copy-out: consecutive slots -> consecutive global addrs
        for (int i = t; i < csize; i += 256) {
            const int b = sbucket[i];
            cv_tmp[(size_t)b * BPAD + gbase[b] + (i - lstart[b])] = stage[i];
        }
        __syncthreads();
    }
}

// ---------------------------------------------------------------------------
// per-bucket row sort (LDS 256-bin counting sort). Block b reads its bucket's
// padded run (count = bcursor[b]), writes row-sorted (col,val) into cv's
// padded bucket region, and row_se[row] = (abs start, abs end).
// ---------------------------------------------------------------------------
__global__ void rowsort_kernel(const int* __restrict__ bcursor,
                               const int2* __restrict__ cv_tmp,
                               int2* __restrict__ cv,
                               int2* __restrict__ row_se) {
    __shared__ int hist[BROWS];
    __shared__ int sstart[BROWS];
    __shared__ int cursor[BROWS];
    const int b = blockIdx.x;
    const int t = threadIdx.x;            // blockDim = 256
    const int base = b * BPAD;
    const int count = bcursor[b];
    hist[t] = 0;
    __syncthreads();
    for (int e = t; e < count; e += 256)
        atomicAdd(&hist[(cv_tmp[base + e].x >> 18) & (BROWS - 1)], 1);
    __syncthreads();
    if (t < 64) {                         // wave 0 scans the 256 bins
        int carry = 0;
        for (int bb = 0; bb < BROWS; bb += 64) {
            const int x = hist[bb + t];
            int v = x;
            #pragma unroll
            for (int d = 1; d < 64; d <<= 1) {
                int y = __shfl_up(v, d);
                if (t >= d) v += y;
            }
            sstart[bb + t] = carry + v - x;
            carry += __shfl(v, 63);
        }
    }
    __syncthreads();
    cursor[t] = sstart[t];
    const int grow = (b << BSHIFT) + t;
    if (grow < N_NODES)
        row_se[grow] = make_int2(base + sstart[t], base + sstart[t] + hist[t]);
    __syncthreads();
    for (int e = t; e < count; e += 256) {
        const int2 p = cv_tmp[base + e];
        const int lr = (p.x >> 18) & (BROWS - 1);
        const int pos = base + atomicAdd(&cursor[lr], 1);
        cv[pos] = make_int2(p.x & COL_MASK, p.y);
    }
}

// ---------------------------------------------------------------------------
// CSR SpMM, fp16 in, f32 accumulate. 16 lanes per row, 4 rows per wave:
// no cross-lane ops. (col,val) is a 16-lane broadcast load; 8-deep unroll
// keeps 8 cv + 8 gather loads in flight per group. Lane l holds dims
// [4l, 4l+4). last=1 fuses pooling: pooled = L0+L1+L2+acc (f32).
// ---------------------------------------------------------------------------
__global__ __launch_bounds__(256) void spmm_kernel(const int2* __restrict__ row_se,
                                                   const int2* __restrict__ cv,
                                                   const __half* __restrict__ in,
                                                   __half* __restrict__ out,
                                                   const __half* __restrict__ P0,
                                                   const __half* __restrict__ P1,
                                                   float* __restrict__ pooled,
                                                   int last) {
    const int row = (blockIdx.x * blockDim.x + threadIdx.x) >> 4;
    const int l   = threadIdx.x & 15;
    if (row >= N_NODES) return;
    const int2 se = row_se[row];
    float a0 = 0.f, a1 = 0.f, a2 = 0.f, a3 = 0.f;
    for (int e = se.x; e < se.y; e += 8) {
        #pragma unroll
        for (int u = 0; u < 8; ++u) {
            const int ee = e + u;
            const bool valid = ee < se.y;
            const int2 p = cv[valid ? ee : se.x];          // clamped: always in-bounds
            const float v = valid ? __int_as_float(p.y) : 0.f;
            const float2 raw = *(const float2*)&in[((size_t)p.x << 6) + (l << 2)];
            union { float2 f; __half2 h[2]; } q; q.f = raw;
            const float2 x0 = __half22float2(q.h[0]);
            const float2 x1 = __half22float2(q.h[1]);
            a0 = fmaf(v, x0.x, a0); a1 = fmaf(v, x0.y, a1);
            a2 = fmaf(v, x1.x, a2); a3 = fmaf(v, x1.y, a3);
        }
    }
    const size_t off = ((size_t)row << 6) + (l << 2);
    if (!last) {
        union { float2 f; __half2 h[2]; } o;
        o.h[0] = __floats2half2_rn(a0, a1);
        o.h[1] = __floats2half2_rn(a2, a3);
        *(float2*)&out[off] = o.f;
    } else {
        union { float2 f; __half2 h[2]; } q0, q1, q2;
        q0.f = *(const float2*)&P0[off];       // L0 row slice
        q1.f = *(const float2*)&P1[off];       // L1 row slice
        q2.f = *(const float2*)&in[off];       // L2 row slice (== gather source)
        const float2 s00 = __half22float2(q0.h[0]), s01 = __half22float2(q0.h[1]);
        const float2 s10 = __half22float2(q1.h[0]), s11 = __half22float2(q1.h[1]);
        const float2 s20 = __half22float2(q2.h[0]), s21 = __half22float2(q2.h[1]);
        *(float4*)&pooled[off] = make_float4(a0 + s00.x + s10.x + s20.x,
                                             a1 + s00.y + s10.y + s20.y,
                                             a2 + s01.x + s11.x + s21.x,
                                             a3 + s01.y + s11.y + s21.y);
    }
}

extern "C" void kernel_launch(void* const* d_in, const int* in_sizes, int n_in,
                              void* d_out, int out_size, void* d_ws, size_t ws_size,
                              hipStream_t stream) {
    const float* user = (const float*)d_in[0];
    const float* item = (const float*)d_in[1];
    const int*   rows = (const int*)d_in[2];
    const int*   cols = (const int*)d_in[3];
    const float* vals = (const float*)d_in[4];

    float* pooled = (float*)d_out;

    // workspace layout. cv_tmp overlays L1+L2 (51.2 MB >= 32 MB): it is dead
    // after rowsort, before spmm1 first writes L1.
    char* p = (char*)d_ws;
    const size_t embB = (size_t)N_NODES * D * 2;    // 25.6 MB per fp16 layer
    __half* L0 = (__half*)p;  p += embB;
    __half* L1 = (__half*)p;  p += embB;
    __half* L2 = (__half*)p;  p += embB;
    int2* cv_tmp = (int2*)L1;                       // overlay, 32 MB
    int2* cv     = (int2*)p;   p += (size_t)N_BUCKETS * BPAD * 8;   // 32 MB
    int2* row_se = (int2*)p;   p += (size_t)N_NODES * 8;            // 1.6 MB
    int*  bcursor = (int*)p;   p += (size_t)N_BUCKETS * 4;

    const dim3 blk256(256);
    hipMemsetAsync(bcursor, 0, (size_t)N_BUCKETS * 4, stream);

    init_kernel<<<2048, blk256, 0, stream>>>(user, item, L0);
    scatter_kernel<<<(N_EDGES + SCATTER_CHUNK - 1) / SCATTER_CHUNK, blk256, 0, stream>>>(
        rows, cols, vals, bcursor, cv_tmp);
    rowsort_kernel<<<N_BUCKETS, blk256, 0, stream>>>(bcursor, cv_tmp, cv, row_se);

    const dim3 grid_spmm((N_NODES * 16 + 255) / 256);   // 16 rows per block
    spmm_kernel<<<grid_spmm, blk256, 0, stream>>>(row_se, cv, L0, L1, nullptr, nullptr, nullptr, 0);
    spmm_kernel<<<grid_spmm, blk256, 0, stream>>>(row_se, cv, L1, L2, nullptr, nullptr, nullptr, 0);
    spmm_kernel<<<grid_spmm, blk256, 0, stream>>>(row_se, cv, L2, nullptr, L0, L1, pooled, 1);
}